// Round 20
// baseline (206.425 us; speedup 1.0000x reference)
//
#include <hip/hip_runtime.h>

typedef unsigned int u32;

#define NPTS 65536
#define G    24
#define NC   (G*G*G)      // 13824 cells, ~4.7 pts/cell UNIFORM after CDF transform
#define CPT  14           // ceil(NC/1024) for the scan

// ws byte offsets (total ~2.32 MB)
#define CNTA_OFF 0u
#define CNTB_OFF (CNTA_OFF + NC*4u)
#define HDRA_OFF (CNTB_OFF + NC*4u)        // uint2 (start,count) per cell, 8-aligned
#define HDRB_OFF (HDRA_OFF + NC*8u)
#define SRTA_OFF (HDRB_OFF + NC*8u)
#define SRTB_OFF (SRTA_OFF + NPTS*16u)

__device__ __forceinline__ int clampi(int v, int lo, int hi) {
    return v < lo ? lo : (v > hi ? hi : v);
}

// Per-axis Gaussian CDF binning (r16-r19-validated, absmax 0.0). Monotone in
// the coordinate -> cell ranges of [q-rad, q+rad] bound the Euclidean ball.
__device__ __forceinline__ int cell1(float x) {
    const float kk = 0.07071067811865475f;   // 1/(10*sqrt(2))
    return clampi((int)(0.5f * erfcf(-x * kk) * (float)G), 0, G - 1);
}
__device__ __forceinline__ void cell3(float x, float y, float z,
                                      int& cx, int& cy, int& cz) {
    cx = cell1(x); cy = cell1(y); cz = cell1(z);
}

// ---- 1. per-cell histogram (verbatim r18/r19) ----
__global__ __launch_bounds__(256) void count_kernel(
    const float* __restrict__ A, const float* __restrict__ B,
    unsigned char* __restrict__ ws)
{
    const int i = blockIdx.x * 256 + threadIdx.x;   // 0..131071
    const int cloud = i >= NPTS;
    const int p = i & (NPTS - 1);
    const float* __restrict__ P = cloud ? B : A;
    u32* cnt = (u32*)(ws + (cloud ? CNTB_OFF : CNTA_OFF));
    int cx, cy, cz;
    cell3(P[p * 3], P[p * 3 + 1], P[p * 3 + 2], cx, cy, cz);
    atomicAdd(&cnt[(cz * G + cy) * G + cx], 1u);
}

// ---- 2. exclusive scan -> hdr[c] = (start, count) (verbatim r18/r19) ----
__global__ __launch_bounds__(1024) void scan_kernel(unsigned char* __restrict__ ws)
{
    const int cloud = blockIdx.x;
    const u32* cnt = (const u32*)(ws + (cloud ? CNTB_OFF : CNTA_OFF));
    uint2* hdr = (uint2*)(ws + (cloud ? HDRB_OFF : HDRA_OFF));
    const int t = threadIdx.x;

    u32 s = 0;
#pragma unroll
    for (int k = 0; k < CPT; ++k) {
        const int c = t * CPT + k;
        s += (c < NC) ? cnt[c] : 0u;
    }
    __shared__ u32 lds[1024];
    lds[t] = s;
    __syncthreads();
    for (int o = 1; o < 1024; o <<= 1) {
        const u32 v = (t >= o) ? lds[t - o] : 0u;
        __syncthreads();
        lds[t] += v;
        __syncthreads();
    }
    u32 run = lds[t] - s;
#pragma unroll
    for (int k = 0; k < CPT; ++k) {
        const int c = t * CPT + k;
        if (c < NC) {
            const u32 n = cnt[c];
            hdr[c] = make_uint2(run, n);
            run += n;
        }
    }
}

// ---- 3. scatter into cell-sorted order (verbatim r18/r19) ----
__global__ __launch_bounds__(256) void scatter_kernel(
    const float* __restrict__ A, const float* __restrict__ B,
    unsigned char* __restrict__ ws)
{
    const int i = blockIdx.x * 256 + threadIdx.x;
    const int cloud = i >= NPTS;
    const int p = i & (NPTS - 1);
    const float* __restrict__ P = cloud ? B : A;
    u32* cnt = (u32*)(ws + (cloud ? CNTB_OFF : CNTA_OFF));
    const uint2* hdr = (const uint2*)(ws + (cloud ? HDRB_OFF : HDRA_OFF));
    float4* srt = (float4*)(ws + (cloud ? SRTB_OFF : SRTA_OFF));

    const float x = P[p * 3], y = P[p * 3 + 1], z = P[p * 3 + 2];
    int cx, cy, cz;
    cell3(x, y, z, cx, cy, cz);
    const int c = (cz * G + cy) * G + cx;
    const u32 old = atomicSub(&cnt[c], 1u);          // count .. 1, unique
    srt[hdr[c].x + old - 1u] = make_float4(x, y, z, 0.0f);
}

// ---- 4. NN query: wave per query-cell, exact two-pass ball query ----
// r19 structure (141 us) + two latency/instruction cuts from the counter
// arithmetic (~540 wave-insts/query, VALUBusy 41% -> latency-dominated):
// (a) FOUR queries per wave in 16-lane groups: per-query scalar overhead
//     (sqrt, XB walks, loop control) paid per 16 lanes; reductions 4-step;
//     pass-1 row (~14 pts) still one round at 16 lanes.
// (b) 2-way ILP in the pass-2 row scan: both loads issue before either is
//     consumed -> dependent-wait depth per row halves (14 -> 7).
// All group conditions (skip, walks, trip counts) are uniform within the
// 16-lane group; masks <= 8 keep shuffles in-group. Exactness unchanged:
// monotone binning + slack-widened box covers the ball.
__global__ __launch_bounds__(256) void query_kernel(
    const unsigned char* __restrict__ ws, float* __restrict__ out)
{
    __shared__ float XB[G + 1];   // Euclidean lower boundary of cell i
    if (threadIdx.x <= G) {
        float v;
        if (threadIdx.x == 0)       v = -3e37f;
        else if (threadIdx.x == G)  v =  3e37f;
        else v = 14.142135623730951f *
                 erfinvf(2.0f * (float)threadIdx.x / (float)G - 1.0f);
        XB[threadIdx.x] = v;
    }
    __syncthreads();

    const int wv   = blockIdx.x * 4 + (threadIdx.x >> 6);   // 0..27647
    const int lane = threadIdx.x & 63;
    const int qtr  = lane >> 4;          // which query of the processed 4
    const int sub  = lane & 15;
    const int dirB = wv >= NC;       // 0: queries=A, DB=B ; 1: queries=B, DB=A
    const int c    = dirB ? wv - NC : wv;
    const int cx = c % G, cy = (c / G) % G, cz = c / (G * G);

    const uint2*  __restrict__ qhdr = (const uint2*)(ws + (dirB ? HDRB_OFF : HDRA_OFF));
    const float4* __restrict__ qp   = (const float4*)(ws + (dirB ? SRTB_OFF : SRTA_OFF));
    const uint2*  __restrict__ dhdr = (const uint2*)(ws + (dirB ? HDRA_OFF : HDRB_OFF));
    const float4* __restrict__ dbp  = (const float4*)(ws + (dirB ? SRTA_OFF : SRTB_OFF));

    const uint2 qh = qhdr[c];
    float qsum = 0.0f;

    if (qh.y != 0) {
        // own-row segment (3 x-contiguous cells), shared by all queries here
        const int x0 = max(cx - 1, 0), x1 = min(cx + 1, G - 1);
        const int rowb = (cz * G + cy) * G;
        const uint2 h0 = dhdr[rowb + x0];          // broadcast loads
        const uint2 h1 = dhdr[rowb + x1];
        const u32 s0 = h0.x, s1 = h1.x + h1.y;

        for (u32 j = 0; j < qh.y; j += 4) {
            const u32  jj  = j + (u32)qtr;         // this group's query
            const bool act = jj < qh.y;
            const float4 q = qp[qh.x + (act ? jj : 0u)];
            float best = 3.4e38f;

            // ---- pass 1: own row -> upper bound (16 lanes per group) ----
            for (u32 k = s0 + sub; k < s1; k += 16) {
                const float4 p = dbp[k];
                const float dx = q.x - p.x, dy = q.y - p.y, dz = q.z - p.z;
                best = fminf(best, fmaf(dx, dx, fmaf(dy, dy, dz * dz)));
            }
#pragma unroll
            for (int m = 1; m <= 8; m <<= 1)
                best = fminf(best, __shfl_xor(best, m, 64));   // in-group

            // ---- pass 2: exact ball cover; bounds via XB walks ----
            const float rad = sqrtf(best) + 1e-3f;
            const float qxl = q.x - rad - 1e-3f, qxh = q.x + rad + 1e-3f;
            const float qyl = q.y - rad - 1e-3f, qyh = q.y + rad + 1e-3f;
            const float qzl = q.z - rad - 1e-3f, qzh = q.z + rad + 1e-3f;
            int lox = cx; while (lox > 0     && XB[lox]     > qxl) --lox;
            int hix = cx; while (hix < G - 1 && XB[hix + 1] < qxh) ++hix;
            int loy = cy; while (loy > 0     && XB[loy]     > qyl) --loy;
            int hiy = cy; while (hiy < G - 1 && XB[hiy + 1] < qyh) ++hiy;
            int loz = cz; while (loz > 0     && XB[loz]     > qzl) --loz;
            int hiz = cz; while (hiz < G - 1 && XB[hiz + 1] < qzh) ++hiz;

            const bool skip = (lox >= x0) && (hix <= x1) &&
                              (loy == cy) && (hiy == cy) &&
                              (loz == cz) && (hiz == cz);
            if (!skip) {   // group-uniform condition
                const int ny = hiy - loy + 1;
                const int R  = ny * (hiz - loz + 1);      // rows (z,y)
                for (int rb = 0; rb < R; rb += 16) {
                    const int r = rb + sub;
                    if (r < R) {
                        const int yy = loy + r % ny;
                        const int zz = loz + r / ny;
                        const int base = (zz * G + yy) * G;
                        const uint2 ha = dhdr[base + lox];
                        const uint2 hb = dhdr[base + hix];
                        const u32 e = hb.x + hb.y;
                        u32 k = ha.x;
                        // 2-way ILP: both loads issue before consumption
                        for (; k + 1 < e; k += 2) {
                            const float4 p0 = dbp[k];
                            const float4 p1 = dbp[k + 1];
                            const float dx0 = q.x - p0.x, dy0 = q.y - p0.y, dz0 = q.z - p0.z;
                            const float dx1 = q.x - p1.x, dy1 = q.y - p1.y, dz1 = q.z - p1.z;
                            best = fminf(best, fmaf(dx0, dx0, fmaf(dy0, dy0, dz0 * dz0)));
                            best = fminf(best, fmaf(dx1, dx1, fmaf(dy1, dy1, dz1 * dz1)));
                        }
                        if (k < e) {
                            const float4 p = dbp[k];
                            const float dx = q.x - p.x, dy = q.y - p.y, dz = q.z - p.z;
                            best = fminf(best, fmaf(dx, dx, fmaf(dy, dy, dz * dz)));
                        }
                    }
                }
#pragma unroll
                for (int m = 1; m <= 8; m <<= 1)
                    best = fminf(best, __shfl_xor(best, m, 64));   // in-group
            }

            // all groups reconverged: collect the 4 results on lane 0
            const float b1 = __shfl(best, 16, 64);
            const float b2 = __shfl(best, 32, 64);
            const float b3 = __shfl(best, 48, 64);
            if (lane == 0) {
                qsum += best;                          // query j (valid)
                if (j + 1 < qh.y) qsum += b1;
                if (j + 2 < qh.y) qsum += b2;
                if (j + 3 < qh.y) qsum += b3;
            }
        }
    }

    __shared__ float wsum[4];
    if (lane == 0) wsum[threadIdx.x >> 6] = qsum;
    __syncthreads();
    if (threadIdx.x == 0)
        atomicAdd(out, (wsum[0] + wsum[1] + wsum[2] + wsum[3]) * (1.0f / (float)NPTS));
}

// ============================================================================
extern "C" void kernel_launch(void* const* d_in, const int* in_sizes, int n_in,
                              void* d_out, int out_size, void* d_ws, size_t ws_size,
                              hipStream_t stream)
{
    const float* A = (const float*)d_in[0];   // pc0 (65536,3) f32
    const float* B = (const float*)d_in[1];   // pc1 (65536,3) f32
    float* out = (float*)d_out;               // scalar f32
    unsigned char* ws = (unsigned char*)d_ws;

    hipMemsetAsync(ws + CNTA_OFF, 0, 2u * NC * 4u, stream);   // cntA + cntB
    hipMemsetAsync(out, 0, sizeof(float), stream);

    count_kernel  <<<(2 * NPTS) / 256, 256, 0, stream>>>(A, B, ws);
    scan_kernel   <<<2, 1024, 0, stream>>>(ws);
    scatter_kernel<<<(2 * NPTS) / 256, 256, 0, stream>>>(A, B, ws);
    query_kernel  <<<(2 * NC) / 4, 256, 0, stream>>>(ws, out);
}

// Round 21
// 167.854 us; speedup vs baseline: 1.2298x; 1.2298x over previous
//
#include <hip/hip_runtime.h>

typedef unsigned int u32;

#define NPTS 65536
#define G    24
#define NC   (G*G*G)      // 13824 cells, ~4.7 pts/cell UNIFORM after CDF transform
#define CPT  14           // ceil(NC/1024) for the scan

// ws byte offsets (total ~2.32 MB)
#define CNTA_OFF 0u
#define CNTB_OFF (CNTA_OFF + NC*4u)
#define HDRA_OFF (CNTB_OFF + NC*4u)        // uint2 (start,count) per cell, 8-aligned
#define HDRB_OFF (HDRA_OFF + NC*8u)
#define SRTA_OFF (HDRB_OFF + NC*8u)
#define SRTB_OFF (SRTA_OFF + NPTS*16u)

__device__ __forceinline__ int clampi(int v, int lo, int hi) {
    return v < lo ? lo : (v > hi ? hi : v);
}

// Per-axis Gaussian CDF binning (r16-r20-validated, absmax 0.0). Monotone in
// the coordinate -> cell ranges of [q-rad, q+rad] bound the Euclidean ball.
__device__ __forceinline__ int cell1(float x) {
    const float kk = 0.07071067811865475f;   // 1/(10*sqrt(2))
    return clampi((int)(0.5f * erfcf(-x * kk) * (float)G), 0, G - 1);
}
__device__ __forceinline__ void cell3(float x, float y, float z,
                                      int& cx, int& cy, int& cz) {
    cx = cell1(x); cy = cell1(y); cz = cell1(z);
}

// ---- 1. per-cell histogram (verbatim r18/r19) ----
__global__ __launch_bounds__(256) void count_kernel(
    const float* __restrict__ A, const float* __restrict__ B,
    unsigned char* __restrict__ ws)
{
    const int i = blockIdx.x * 256 + threadIdx.x;   // 0..131071
    const int cloud = i >= NPTS;
    const int p = i & (NPTS - 1);
    const float* __restrict__ P = cloud ? B : A;
    u32* cnt = (u32*)(ws + (cloud ? CNTB_OFF : CNTA_OFF));
    int cx, cy, cz;
    cell3(P[p * 3], P[p * 3 + 1], P[p * 3 + 2], cx, cy, cz);
    atomicAdd(&cnt[(cz * G + cy) * G + cx], 1u);
}

// ---- 2. exclusive scan -> hdr[c] = (start, count) (verbatim r18/r19) ----
__global__ __launch_bounds__(1024) void scan_kernel(unsigned char* __restrict__ ws)
{
    const int cloud = blockIdx.x;
    const u32* cnt = (const u32*)(ws + (cloud ? CNTB_OFF : CNTA_OFF));
    uint2* hdr = (uint2*)(ws + (cloud ? HDRB_OFF : HDRA_OFF));
    const int t = threadIdx.x;

    u32 s = 0;
#pragma unroll
    for (int k = 0; k < CPT; ++k) {
        const int c = t * CPT + k;
        s += (c < NC) ? cnt[c] : 0u;
    }
    __shared__ u32 lds[1024];
    lds[t] = s;
    __syncthreads();
    for (int o = 1; o < 1024; o <<= 1) {
        const u32 v = (t >= o) ? lds[t - o] : 0u;
        __syncthreads();
        lds[t] += v;
        __syncthreads();
    }
    u32 run = lds[t] - s;
#pragma unroll
    for (int k = 0; k < CPT; ++k) {
        const int c = t * CPT + k;
        if (c < NC) {
            const u32 n = cnt[c];
            hdr[c] = make_uint2(run, n);
            run += n;
        }
    }
}

// ---- 3. scatter into cell-sorted order (verbatim r18/r19) ----
__global__ __launch_bounds__(256) void scatter_kernel(
    const float* __restrict__ A, const float* __restrict__ B,
    unsigned char* __restrict__ ws)
{
    const int i = blockIdx.x * 256 + threadIdx.x;
    const int cloud = i >= NPTS;
    const int p = i & (NPTS - 1);
    const float* __restrict__ P = cloud ? B : A;
    u32* cnt = (u32*)(ws + (cloud ? CNTB_OFF : CNTA_OFF));
    const uint2* hdr = (const uint2*)(ws + (cloud ? HDRB_OFF : HDRA_OFF));
    float4* srt = (float4*)(ws + (cloud ? SRTB_OFF : SRTA_OFF));

    const float x = P[p * 3], y = P[p * 3 + 1], z = P[p * 3 + 2];
    int cx, cy, cz;
    cell3(x, y, z, cx, cy, cz);
    const int c = (cz * G + cy) * G + cx;
    const u32 old = atomicSub(&cnt[c], 1u);          // count .. 1, unique
    srt[hdr[c].x + old - 1u] = make_float4(x, y, z, 0.0f);
}

// ---- 4. NN query: wave per query-cell, exact two-pass ball query ----
// EXACTLY the r19 structure (141 us champion: two queries per wave in
// 32-lane halves — r20 showed 4x16 groups serialize divergent pass-2
// branches and regress) + ONE change: 2-way ILP in the pass-2 row scan
// (issue dbp[k] and dbp[k+1] before consuming either -> dependent-wait
// depth per row halves). Exactness unchanged: monotone binning +
// slack-widened box covers the ball.
__global__ __launch_bounds__(256) void query_kernel(
    const unsigned char* __restrict__ ws, float* __restrict__ out)
{
    __shared__ float XB[G + 1];   // Euclidean lower boundary of cell i
    if (threadIdx.x <= G) {
        float v;
        if (threadIdx.x == 0)       v = -3e37f;
        else if (threadIdx.x == G)  v =  3e37f;
        else v = 14.142135623730951f *
                 erfinvf(2.0f * (float)threadIdx.x / (float)G - 1.0f);
        XB[threadIdx.x] = v;
    }
    __syncthreads();

    const int wv   = blockIdx.x * 4 + (threadIdx.x >> 6);   // 0..27647
    const int lane = threadIdx.x & 63;
    const int half = lane >> 5;          // which query of the processed pair
    const int sub  = lane & 31;
    const int dirB = wv >= NC;       // 0: queries=A, DB=B ; 1: queries=B, DB=A
    const int c    = dirB ? wv - NC : wv;
    const int cx = c % G, cy = (c / G) % G, cz = c / (G * G);

    const uint2*  __restrict__ qhdr = (const uint2*)(ws + (dirB ? HDRB_OFF : HDRA_OFF));
    const float4* __restrict__ qp   = (const float4*)(ws + (dirB ? SRTB_OFF : SRTA_OFF));
    const uint2*  __restrict__ dhdr = (const uint2*)(ws + (dirB ? HDRA_OFF : HDRB_OFF));
    const float4* __restrict__ dbp  = (const float4*)(ws + (dirB ? SRTA_OFF : SRTB_OFF));

    const uint2 qh = qhdr[c];
    float qsum = 0.0f;

    if (qh.y != 0) {
        // own-row segment (3 x-contiguous cells), shared by all queries here
        const int x0 = max(cx - 1, 0), x1 = min(cx + 1, G - 1);
        const int rowb = (cz * G + cy) * G;
        const uint2 h0 = dhdr[rowb + x0];          // broadcast loads
        const uint2 h1 = dhdr[rowb + x1];
        const u32 s0 = h0.x, s1 = h1.x + h1.y;

        for (u32 j = 0; j < qh.y; j += 2) {
            const u32  jj  = j + (u32)half;        // this half's query
            const bool act = jj < qh.y;
            const float4 q = qp[qh.x + (act ? jj : 0u)];
            float best = 3.4e38f;

            // ---- pass 1: own row -> upper bound (32 lanes per half) ----
            for (u32 k = s0 + sub; k < s1; k += 32) {
                const float4 p = dbp[k];
                const float dx = q.x - p.x, dy = q.y - p.y, dz = q.z - p.z;
                best = fminf(best, fmaf(dx, dx, fmaf(dy, dy, dz * dz)));
            }
#pragma unroll
            for (int m = 1; m <= 16; m <<= 1)
                best = fminf(best, __shfl_xor(best, m, 64));   // in-half

            // ---- pass 2: exact ball cover; bounds via XB walks ----
            const float rad = sqrtf(best) + 1e-3f;
            const float qxl = q.x - rad - 1e-3f, qxh = q.x + rad + 1e-3f;
            const float qyl = q.y - rad - 1e-3f, qyh = q.y + rad + 1e-3f;
            const float qzl = q.z - rad - 1e-3f, qzh = q.z + rad + 1e-3f;
            int lox = cx; while (lox > 0     && XB[lox]     > qxl) --lox;
            int hix = cx; while (hix < G - 1 && XB[hix + 1] < qxh) ++hix;
            int loy = cy; while (loy > 0     && XB[loy]     > qyl) --loy;
            int hiy = cy; while (hiy < G - 1 && XB[hiy + 1] < qyh) ++hiy;
            int loz = cz; while (loz > 0     && XB[loz]     > qzl) --loz;
            int hiz = cz; while (hiz < G - 1 && XB[hiz + 1] < qzh) ++hiz;

            const bool skip = (lox >= x0) && (hix <= x1) &&
                              (loy == cy) && (hiy == cy) &&
                              (loz == cz) && (hiz == cz);
            if (!skip) {   // half-uniform condition (best/walk uniform in half)
                const int ny = hiy - loy + 1;
                const int R  = ny * (hiz - loz + 1);      // rows (z,y)
                for (int rb = 0; rb < R; rb += 32) {
                    const int r = rb + sub;
                    if (r < R) {
                        const int yy = loy + r % ny;
                        const int zz = loz + r / ny;
                        const int base = (zz * G + yy) * G;
                        const uint2 ha = dhdr[base + lox];
                        const uint2 hb = dhdr[base + hix];
                        const u32 e = hb.x + hb.y;
                        u32 k = ha.x;
                        // 2-way ILP: both loads issue before consumption
                        for (; k + 1 < e; k += 2) {
                            const float4 p0 = dbp[k];
                            const float4 p1 = dbp[k + 1];
                            const float dx0 = q.x - p0.x, dy0 = q.y - p0.y, dz0 = q.z - p0.z;
                            const float dx1 = q.x - p1.x, dy1 = q.y - p1.y, dz1 = q.z - p1.z;
                            best = fminf(best, fmaf(dx0, dx0, fmaf(dy0, dy0, dz0 * dz0)));
                            best = fminf(best, fmaf(dx1, dx1, fmaf(dy1, dy1, dz1 * dz1)));
                        }
                        if (k < e) {
                            const float4 p = dbp[k];
                            const float dx = q.x - p.x, dy = q.y - p.y, dz = q.z - p.z;
                            best = fminf(best, fmaf(dx, dx, fmaf(dy, dy, dz * dz)));
                        }
                    }
                }
#pragma unroll
                for (int m = 1; m <= 16; m <<= 1)
                    best = fminf(best, __shfl_xor(best, m, 64));   // in-half
            }

            // both halves reconverged here: collect pair results on lane 0
            const float b1 = __shfl(best, 32, 64);
            if (lane == 0) {
                qsum += best;                        // query j (always valid)
                if (j + 1 < qh.y) qsum += b1;        // query j+1 if it exists
            }
        }
    }

    __shared__ float wsum[4];
    if (lane == 0) wsum[threadIdx.x >> 6] = qsum;
    __syncthreads();
    if (threadIdx.x == 0)
        atomicAdd(out, (wsum[0] + wsum[1] + wsum[2] + wsum[3]) * (1.0f / (float)NPTS));
}

// ============================================================================
extern "C" void kernel_launch(void* const* d_in, const int* in_sizes, int n_in,
                              void* d_out, int out_size, void* d_ws, size_t ws_size,
                              hipStream_t stream)
{
    const float* A = (const float*)d_in[0];   // pc0 (65536,3) f32
    const float* B = (const float*)d_in[1];   // pc1 (65536,3) f32
    float* out = (float*)d_out;               // scalar f32
    unsigned char* ws = (unsigned char*)d_ws;

    hipMemsetAsync(ws + CNTA_OFF, 0, 2u * NC * 4u, stream);   // cntA + cntB
    hipMemsetAsync(out, 0, sizeof(float), stream);

    count_kernel  <<<(2 * NPTS) / 256, 256, 0, stream>>>(A, B, ws);
    scan_kernel   <<<2, 1024, 0, stream>>>(ws);
    scatter_kernel<<<(2 * NPTS) / 256, 256, 0, stream>>>(A, B, ws);
    query_kernel  <<<(2 * NC) / 4, 256, 0, stream>>>(ws, out);
}